// Round 10
// baseline (298.550 us; speedup 1.0000x reference)
//
#include <hip/hip_runtime.h>
#include <cstdint>

// AdaptiveLoss: adaptive-softmax NLL.  5 launches:
//   1. cvt_feat   : f32->bf16 for features ONLY (4MB; weights stay f32).
//   2. gemm_all   : proj GEMMs (A=Xb bf16 gload_lds, B=proj f32 reg-staged
//                   with inline RNE cvt -> ds_write), C bf16 -> Hact.
//   3. gemm_all   : single mega (head + c0..c3, 6280 blocks, B=f32 weights
//                   direct) -> sum-exp partials part[row][785] + head gates.
//   4. gather_rows: in-block LSE + cluster-sorted targets + exact-trip dots
//                   reading f32 weight rows (rounded through bf16 per elem:
//                   bit-identical to R9) + fused row loss.
//   5. final_sum.
// R10 vs R9 (292.1 us): delete the B-operand bf16 round-trip. cvt was
// 107.5MB f32 read + 53.7MB bf16 write, mega re-read the 53.7MB: ~161MB of
// traffic replaced by mega reading 107.5MB f32 once (~-26 us cvt, ~+8-12 us
// mega staging). Rounding chain unchanged (RNE everywhere) -> bit-identical.
// Mega compute/LDS-layout/swizzle untouched; only the B staging path differs.

typedef unsigned short u16;
typedef __attribute__((ext_vector_type(4))) float f32x4;
typedef __attribute__((ext_vector_type(8))) __bf16 bf16x8;
typedef __attribute__((ext_vector_type(4))) unsigned int u32x4;

__device__ __forceinline__ u16 f2bf(float f){
  unsigned u = __float_as_uint(f);
  u += 0x7FFFu + ((u >> 16) & 1u);   // RNE
  return (u16)(u >> 16);
}

__device__ __forceinline__ float wave_sum(float v){
  #pragma unroll
  for (int d = 1; d < 64; d <<= 1) v += __shfl_xor(v, d, 64);
  return v;
}

// async global->LDS, 16B per lane. LDS dest must be wave-uniform base
// (HW adds lane*16); global src is per-lane (carries the XOR pre-swizzle).
__device__ __forceinline__ void gload_lds16(const void* g, void* l){
  __builtin_amdgcn_global_load_lds(
      (const __attribute__((address_space(1))) unsigned int*)g,
      (__attribute__((address_space(3))) unsigned int*)l, 16, 0, 0);
}

// ---------------- convert features f32 -> bf16 (4MB, one launch) ----------------
__global__ __launch_bounds__(256) void cvt_feat(const float* src, u16* dst, int nchunks){
  int c = blockIdx.x*256 + threadIdx.x;
  if (c < nchunks){
    const float4* sp = (const float4*)src + (size_t)c*2;
    float4 f0 = sp[0], f1 = sp[1];
    uint4 d;
    d.x = (unsigned)f2bf(f0.x) | ((unsigned)f2bf(f0.y) << 16);
    d.y = (unsigned)f2bf(f0.z) | ((unsigned)f2bf(f0.w) << 16);
    d.z = (unsigned)f2bf(f1.x) | ((unsigned)f2bf(f1.y) << 16);
    d.w = (unsigned)f2bf(f1.z) | ((unsigned)f2bf(f1.w) << 16);
    ((uint4*)dst)[c] = d;
  }
}

// ------- unified GEMM: C = A[MxK](bf16) * B[NxK](f32)^T, 128x128 tile, BK=64 ---
// 4 waves 2x2. A staged via global_load_lds (bf16); B staged f32->VGPR->
// RNE-cvt->ds_write_b128 (same linear LDS layout + XOR source swizzle).
// part!=null -> per-(row,tile) sum-exp partials part[row*ldc + tileN];
// else bf16 C store (ldc). gates!=null (head): cols>=10000 -> gates[row*4+i].
struct GSeg { const u16* A; const float* B; float* part; u16* C; float* gates;
              int lda, N, K, ntiles, tileStart, ldc; };
struct GTab { GSeg seg[5]; int nseg; int swz; };

__global__ __launch_bounds__(256, 4) void gemm_all(GTab tab){
  __shared__ __attribute__((aligned(16))) u16 ldsA[128*64];
  __shared__ __attribute__((aligned(16))) u16 ldsB[128*64];
  __shared__ float msLds[128][2];

  int bx = blockIdx.x, by = blockIdx.y;
  if (tab.swz){
    // bijective XCD swizzle, grid (8, nby): hardware XCD ~ flat%8.
    int flat = by * 8 + bx;
    int xcd = flat & 7, j = flat >> 3;
    by = (j >> 3) * 8 + xcd;
    bx = j & 7;
    if (by >= (int)gridDim.y){ by = j; bx = xcd; }  // bijective tail patch
  }

  int s = 0;
  #pragma unroll
  for (int i = 1; i < 5; i++)
    if (i < tab.nseg && by >= tab.seg[i].tileStart) s = i;
  const u16* Ab   = tab.seg[s].A;
  const float* Bf = tab.seg[s].B;
  float* part   = tab.seg[s].part;
  u16* Cc       = tab.seg[s].C;
  float* gatesp = tab.seg[s].gates;
  int lda = tab.seg[s].lda, N = tab.seg[s].N, K = tab.seg[s].K;
  int ldc = tab.seg[s].ldc;
  int tileN = by - tab.seg[s].tileStart;
  int n0 = tileN * 128;
  int row0 = bx * 128;

  int tid = threadIdx.x;
  int wid = tid >> 6, lane = tid & 63;
  int wr = wid >> 1, wc = wid & 1;
  int qr = lane >> 4, ln = lane & 15;

  // staging coords: 1024 chunks (16B-bf16 / 8-elem) per matrix, 4 per thread;
  // XOR swizzle applied to the GLOBAL source k-chunk, LDS written linearly.
  const char* baseA = (const char*)(Ab + (size_t)row0*lda);
  unsigned offA[4], offBe[4];              // offBe in f32 elements
  #pragma unroll
  for (int t = 0; t < 4; t++){
    int c = t*256 + tid, row = c >> 3, jj = (c & 7) ^ (row & 7);
    offA[t] = (unsigned)(row*lda + jj*8) * 2u;
    int nr = n0 + row; if (nr >= N) nr = N - 1;    // clamp; masked in epilogue
    offBe[t] = (unsigned)(nr*K + jj*8);
  }

  f32x4 acc[4][4];
  const f32x4 zero = {0.f, 0.f, 0.f, 0.f};
  #pragma unroll
  for (int i = 0; i < 4; i++)
    #pragma unroll
    for (int j = 0; j < 4; j++) acc[i][j] = zero;

  int nkt = K >> 6;
  for (int kt = 0; kt < nkt; kt++){
    __syncthreads();                       // previous compute done
    unsigned kbA = (unsigned)kt * 128u;    // bytes (bf16)
    unsigned kbE = (unsigned)kt * 64u;     // f32 elements
    // issue B f32 loads first (latency), then A DMA, then B cvt+write
    float4 b0[4], b1[4];
    #pragma unroll
    for (int t = 0; t < 4; t++){
      const float* bp = Bf + offBe[t] + kbE;
      b0[t] = *(const float4*)bp;
      b1[t] = *(const float4*)(bp + 4);
    }
    #pragma unroll
    for (int t = 0; t < 4; t++)
      gload_lds16(baseA + offA[t] + kbA, (char*)ldsA + (size_t)(t*256 + tid)*16);
    #pragma unroll
    for (int t = 0; t < 4; t++){
      bf16x8 w;
      w[0] = (__bf16)b0[t].x; w[1] = (__bf16)b0[t].y;
      w[2] = (__bf16)b0[t].z; w[3] = (__bf16)b0[t].w;
      w[4] = (__bf16)b1[t].x; w[5] = (__bf16)b1[t].y;
      w[6] = (__bf16)b1[t].z; w[7] = (__bf16)b1[t].w;
      *(bf16x8*)((char*)ldsB + (size_t)(t*256 + tid)*16) = w;
    }
    __syncthreads();                       // drains A vmcnt + B lgkm
    #pragma unroll
    for (int ks = 0; ks < 2; ks++){
      bf16x8 av[4], bv[4];
      #pragma unroll
      for (int mt = 0; mt < 4; mt++){
        int rl = wr*64 + mt*16 + ln;
        int ch = rl*8 + ((ks*4 + qr) ^ (rl & 7));
        av[mt] = *(const bf16x8*)((const char*)ldsA + ch*16);
      }
      #pragma unroll
      for (int nt = 0; nt < 4; nt++){
        int rl = wc*64 + nt*16 + ln;
        int ch = rl*8 + ((ks*4 + qr) ^ (rl & 7));
        bv[nt] = *(const bf16x8*)((const char*)ldsB + ch*16);
      }
      #pragma unroll
      for (int mt = 0; mt < 4; mt++)
        #pragma unroll
        for (int nt = 0; nt < 4; nt++)
          acc[mt][nt] = __builtin_amdgcn_mfma_f32_16x16x32_bf16(av[mt], bv[nt], acc[mt][nt], 0, 0, 0);
    }
  }

  if (part){
    // C layout: row = quad*4 + reg, col = lane&15 (per 16x16 tile). Plain sum-exp.
    #pragma unroll
    for (int mt = 0; mt < 4; mt++){
      #pragma unroll
      for (int r = 0; r < 4; r++){
        float ss = 0.f;
        #pragma unroll
        for (int nt = 0; nt < 4; nt++){
          int col = n0 + wc*64 + nt*16 + ln;
          if (col < N){
            float v = acc[mt][nt][r];
            ss += __expf(v);
            if (gatesp && col >= 10000){
              int row = row0 + wr*64 + mt*16 + qr*4 + r;
              gatesp[row*4 + (col - 10000)] = v;
            }
          }
        }
        ss += __shfl_xor(ss, 1, 64);
        ss += __shfl_xor(ss, 2, 64);
        ss += __shfl_xor(ss, 4, 64);
        ss += __shfl_xor(ss, 8, 64);
        if (ln == 0) msLds[wr*64 + mt*16 + qr*4 + r][wc] = ss;
      }
    }
    __syncthreads();
    if (tid < 128)
      part[(size_t)(row0 + tid)*ldc + tileN] = msLds[tid][0] + msLds[tid][1];
  } else {
    #pragma unroll
    for (int mt = 0; mt < 4; mt++)
      #pragma unroll
      for (int nt = 0; nt < 4; nt++)
        #pragma unroll
        for (int r = 0; r < 4; r++){
          int col = n0 + wc*64 + nt*16 + ln;
          if (col < N){
            int row = row0 + wr*64 + mt*16 + qr*4 + r;
            Cc[(size_t)row*ldc + col] = f2bf(acc[mt][nt][r]);
          }
        }
  }
}

// ---- gather helpers: exact-trip dots, LDS bf16 x global f32 (rounded to bf16) ----
__device__ __forceinline__ float dotf8(u32x4 va, const float* wp){
  float4 w0 = *(const float4*)wp, w1 = *(const float4*)(wp + 4);
  float w[8] = {w0.x, w0.y, w0.z, w0.w, w1.x, w1.y, w1.z, w1.w};
  float p = 0.f;
  #pragma unroll
  for (int i = 0; i < 4; i++){
    unsigned ua = va[i];
    p = fmaf(__uint_as_float(ua << 16),         (float)(__bf16)w[2*i],     p);
    p = fmaf(__uint_as_float(ua & 0xFFFF0000u), (float)(__bf16)w[2*i + 1], p);
  }
  return p;
}

template<int T>
__device__ __forceinline__ float dotTf(const u16* a, const float* b, int gl){
  float s = 0.f;
  #pragma unroll
  for (int it = 0; it < T; it++){
    int k = gl*8 + it*128;
    s += dotf8(*(const u32x4*)(a + k), b + k);
  }
  return s;
}

// len=64 variant: one iteration, upper 8 lanes masked
__device__ __forceinline__ float dot1mf(const u16* a, const float* b, int gl){
  int k = gl*8;
  int kc = k < 64 ? k : 0;
  float p = dotf8(*(const u32x4*)(a + kc), b + kc);
  return k < 64 ? p : 0.f;
}

// ------- row-centric: in-block LSE + sorted per-target log-prob + row loss -------
// part is flat [1024 rows][785 global tiles]; segment boundaries within a row:
// head 0..78, c0 79..157, c1 158..314, c2 315..627, c3 628..784.
struct GatherArgs {
  const u16* Xb; const float* HbF; const u16* Hact;
  const float* O0; const float* O1; const float* O2; const float* O3;
  const float* part; const float* gates; const int* targets;
  const float* discard; float* psamp;
};

__global__ __launch_bounds__(256) void gather_rows(GatherArgs g){
  __shared__ __attribute__((aligned(16))) u16 xr[1024];
  __shared__ __attribute__((aligned(16))) u16 hr[960];
  __shared__ __attribute__((aligned(16))) int tg[128];
  __shared__ int tgs[128];                // cluster-sorted targets
  __shared__ int cntW[2][5];              // per-wave bucket counts
  __shared__ float sLse[4][5];
  __shared__ float ls[5], gs[4];
  __shared__ float lpv[128];
  __shared__ float sa[2], sw[2];

  int b = blockIdx.x;
  int tid = threadIdx.x;
  int w = tid >> 6, lane = tid & 63;
  int grp = tid >> 4, gl = tid & 15;      // 16 groups x 16 lanes

  if (tid < 128) ((u32x4*)xr)[tid] = ((const u32x4*)(g.Xb + (size_t)b*1024))[tid];
  else if (tid < 248) ((u32x4*)hr)[tid-128] = ((const u32x4*)(g.Hact + (size_t)b*960))[tid-128];
  if (tid < 32) ((u32x4*)tg)[tid] = ((const u32x4*)(g.targets + (size_t)b*128))[tid];
  if (tid < 4) gs[tid] = g.gates[b*4 + tid];

  // in-block LSE: contiguous coalesced read of this row's 785 partials
  {
    const float* pr = g.part + (size_t)b*785;
    float p0=0.f, p1=0.f, p2=0.f, p3=0.f, p4=0.f;
    for (int j = tid; j < 785; j += 256){
      float v = pr[j];
      if      (j <  79) p0 += v;
      else if (j < 158) p1 += v;
      else if (j < 315) p2 += v;
      else if (j < 628) p3 += v;
      else              p4 += v;
    }
    p0 = wave_sum(p0); p1 = wave_sum(p1); p2 = wave_sum(p2);
    p3 = wave_sum(p3); p4 = wave_sum(p4);
    if (lane == 0){
      sLse[w][0]=p0; sLse[w][1]=p1; sLse[w][2]=p2; sLse[w][3]=p3; sLse[w][4]=p4;
    }
  }
  __syncthreads();                        // staging + sLse visible
  if (tid < 5)
    ls[tid] = __logf(sLse[0][tid] + sLse[1][tid] + sLse[2][tid] + sLse[3][tid]);

  // ---- counting sort by bucket (ballot/popcount); waves 2,3 mirror harmlessly ----
  int vb128 = tg[tid & 127];
  int bkt = (vb128 >= 10000) + (vb128 >= 20000) + (vb128 >= 40000) + (vb128 >= 80000);
  unsigned long long ltm = (1ULL << lane) - 1ULL;
  int rank = 0;
  #pragma unroll
  for (int c = 0; c < 5; c++){
    unsigned long long m = __ballot(bkt == c);
    if (bkt == c) rank = __popcll(m & ltm);
    if (lane == 0 && w < 2) cntW[w][c] = (int)__popcll(m);
  }
  __syncthreads();                        // cntW + ls visible
  if (tid < 128){
    int base = 0;
    #pragma unroll
    for (int c = 0; c < 5; c++)
      base += (c < bkt) ? (cntW[0][c] + cntW[1][c]) : 0;
    int pos = base + (w == 1 ? cntW[0][bkt] : 0) + rank;
    tgs[pos] = vb128;
  }
  __syncthreads();                        // tgs visible

  // ---- per-target log-prob: 16 consecutive sorted targets per iteration ----
  for (int t = 0; t < 8; t++){
    int ti = t*16 + grp;
    int v = tgs[ti];                      // group-uniform; wave-uniform cluster (sorted)
    bool head = v < 10000;
    int c = (v >= 20000) + (v >= 40000) + (v >= 80000);
    float s;
    if (head)       s = dotTf<8>(xr,       g.HbF + (size_t)v*1024, gl);
    else if (c==0)  s = dotTf<4>(hr,       g.O0 + (size_t)(v-10000)*512, gl);
    else if (c==1)  s = dotTf<2>(hr + 512, g.O1 + (size_t)(v-20000)*256, gl);
    else if (c==2)  s = dotTf<1>(hr + 768, g.O2 + (size_t)(v-40000)*128, gl);
    else            s = dot1mf (hr + 896,  g.O3 + (size_t)(v-80000)*64,  gl);
    // 16-lane group reduce (xor < 16 stays inside the group)
    s += __shfl_xor(s, 1, 64);
    s += __shfl_xor(s, 2, 64);
    s += __shfl_xor(s, 4, 64);
    s += __shfl_xor(s, 8, 64);
    float bias = head ? -ls[0] : (gs[c] - ls[0] - ls[c + 1]);   // LDS dyn-index ok
    if (gl == 0) lpv[ti] = s + bias;
  }
  __syncthreads();

  // fused row_loss: per-row weighted mean NLL (order-independent sum;
  // tgs/lpv pairing is consistent by index)
  if (tid < 128){
    int v = tgs[tid];
    float wt = 1.0f - g.discard[v];
    float a  = -lpv[tid] * wt;
    float as = wave_sum(a), ws = wave_sum(wt);
    if (lane == 0){ sa[w] = as; sw[w] = ws; }
  }
  __syncthreads();
  if (tid == 0) g.psamp[b] = (sa[0] + sa[1]) / (sw[0] + sw[1]);
}

__global__ __launch_bounds__(256) void final_sum(const float* psamp, float* out){
  float s = 0.f;
  for (int i = threadIdx.x; i < 1024; i += 256) s += psamp[i];
  s = wave_sum(s);
  __shared__ float sb[4];
  if ((threadIdx.x & 63) == 0) sb[threadIdx.x >> 6] = s;
  __syncthreads();
  if (threadIdx.x == 0) out[0] = (sb[0] + sb[1] + sb[2] + sb[3]) / (1024.0f + 1e-5f);
}

// ---------------- host ----------------
extern "C" void kernel_launch(void* const* d_in, const int* in_sizes, int n_in,
                              void* d_out, int out_size, void* d_ws, size_t ws_size,
                              hipStream_t stream){
  (void)in_sizes; (void)n_in; (void)out_size; (void)ws_size;
  const float* features = (const float*)d_in[0];
  const float* head_w   = (const float*)d_in[1];
  const float* proj[4]  = {(const float*)d_in[2], (const float*)d_in[4],
                           (const float*)d_in[6], (const float*)d_in[8]};
  const float* outw[4]  = {(const float*)d_in[3], (const float*)d_in[5],
                           (const float*)d_in[7], (const float*)d_in[9]};
  const float* discard  = (const float*)d_in[10];
  const int*   targets  = (const int*)d_in[11];
  float* out = (float*)d_out;

  char* wsp = (char*)d_ws;
  size_t off = 0;
  auto carve = [&](size_t bytes)->char*{
    char* p = wsp + off; off += (bytes + 255) & ~(size_t)255; return p;
  };
  u16* Xb     = (u16*)carve(1024ull*1024*2);
  u16* Hact   = (u16*)carve(1024ull*960*2);
  float* part = (float*)carve(803840ull*4);   // 1024 rows x 785 global tiles
  float* gates= (float*)carve(4096*4);
  float* psamp= (float*)carve(1024*4);

  // launch 1: convert features only (1048576 elems = 131072 chunks)
  cvt_feat<<<dim3(512), dim3(256), 0, stream>>>(features, Xb, 131072);

  // launch 2: proj GEMMs (A=Xb bf16, B=proj f32 direct; bf16 C -> Hact)
  GTab tp{};
  tp.nseg = 4; tp.swz = 0;
  tp.seg[0] = {Xb, proj[0], nullptr, Hact,       nullptr, 1024, 512, 1024, 4, 0, 960};
  tp.seg[1] = {Xb, proj[1], nullptr, Hact + 512, nullptr, 1024, 256, 1024, 2, 4, 960};
  tp.seg[2] = {Xb, proj[2], nullptr, Hact + 768, nullptr, 1024, 128, 1024, 1, 6, 960};
  tp.seg[3] = {Xb, proj[3], nullptr, Hact + 896, nullptr, 1024, 64,  1024, 1, 7, 960};
  gemm_all<<<dim3(8, 8), dim3(256), 0, stream>>>(tp);

  // launch 3: mega — head + all 4 cluster GEMMs (B = f32 weights direct),
  // 6280 blocks. part[row][785]: per-seg pointer = part + global tile base.
  GTab tm{};
  tm.nseg = 5; tm.swz = 1;
  tm.seg[0] = {Xb,         head_w,  part,       nullptr, gates,   1024, 10004, 1024, 79,  0,   785};
  tm.seg[1] = {Hact,       outw[0], part + 79,  nullptr, nullptr, 960,  10000, 512,  79,  79,  785};
  tm.seg[2] = {Hact + 512, outw[1], part + 158, nullptr, nullptr, 960,  20000, 256,  157, 158, 785};
  tm.seg[3] = {Hact + 768, outw[2], part + 315, nullptr, nullptr, 960,  40000, 128,  313, 315, 785};
  tm.seg[4] = {Hact + 896, outw[3], part + 628, nullptr, nullptr, 960,  20000, 64,   157, 628, 785};
  gemm_all<<<dim3(8, 785), dim3(256), 0, stream>>>(tm);

  // launch 4: gather (in-block LSE + sorted target log-probs + row loss)
  GatherArgs ga{Xb, head_w, Hact, outw[0], outw[1], outw[2], outw[3],
                part, gates, targets, discard, psamp};
  gather_rows<<<dim3(1024), dim3(256), 0, stream>>>(ga);

  // launch 5: final reduction
  final_sum<<<dim3(1), dim3(256), 0, stream>>>(psamp, out);
}